// Round 4
// baseline (723.955 us; speedup 1.0000x reference)
//
#include <hip/hip_runtime.h>
#include <hip/hip_bf16.h>
#include <cstdint>

#define NNODES 100000
#define NEDGES 1000000
#define HDIM 64
#define ODIM 16
#define NB 8
#define NREL 90
#define KDIM (HDIM * NB)   // 512 = GEMM inner dim, k = i*8 + b

typedef short short8 __attribute__((ext_vector_type(8)));
typedef float f32x4  __attribute__((ext_vector_type(4)));
union FragU { uint4 u; short8 s; };

__device__ __forceinline__ float asf(uint32_t u) { float f; __builtin_memcpy(&f, &u, 4); return f; }
__device__ __forceinline__ uint32_t asu(float f) { uint32_t u; __builtin_memcpy(&u, &f, 4); return u; }
__device__ __forceinline__ uint16_t f2bf(float f) {
    uint32_t x = asu(f);
    return (uint16_t)((x + 0x7FFFu + ((x >> 16) & 1u)) >> 16);
}
__device__ __forceinline__ uint32_t pack2(float lo, float hi) {
    return (uint32_t)f2bf(lo) | ((uint32_t)f2bf(hi) << 16);
}
__device__ __forceinline__ void fmaC(const float4& cA, const float4& cB, float xs,
                                     float* __restrict__ acc) {
    acc[0] = fmaf(cA.x, xs, acc[0]); acc[1] = fmaf(cA.y, xs, acc[1]);
    acc[2] = fmaf(cA.z, xs, acc[2]); acc[3] = fmaf(cA.w, xs, acc[3]);
    acc[4] = fmaf(cB.x, xs, acc[4]); acc[5] = fmaf(cB.y, xs, acc[5]);
    acc[6] = fmaf(cB.z, xs, acc[6]); acc[7] = fmaf(cB.w, xs, acc[7]);
}

// ---------------------------------------------------------------------------
// cast: f32 feats -> bf16 x  (4 elems/thread)
// ---------------------------------------------------------------------------
__global__ void cast_kernel(const float* __restrict__ in, uint16_t* __restrict__ out, int n4) {
    const int stride = (int)(gridDim.x * blockDim.x);
    for (int idx = (int)(blockIdx.x * blockDim.x + threadIdx.x); idx < n4; idx += stride) {
        float4 v = reinterpret_cast<const float4*>(in)[idx];
        uint2 p;
        p.x = pack2(v.x, v.y);
        p.y = pack2(v.z, v.w);
        reinterpret_cast<uint2*>(out)[idx] = p;
    }
}

// ---------------------------------------------------------------------------
// CSR build: histogram by dst -> exclusive scan -> scatter packed edge recs
// rec[e] = { src | (etype<<20), norm }  (8 B)
// ---------------------------------------------------------------------------
__global__ void zero_kernel(int* __restrict__ p, int n) {
    for (int i = (int)(blockIdx.x * blockDim.x + threadIdx.x); i < n;
         i += (int)(gridDim.x * blockDim.x)) p[i] = 0;
}

__global__ void hist_kernel(const int* __restrict__ dst, int* __restrict__ cnt, int nE) {
    for (int e = (int)(blockIdx.x * blockDim.x + threadIdx.x); e < nE;
         e += (int)(gridDim.x * blockDim.x)) atomicAdd(&cnt[dst[e]], 1);
}

#define SCAN_B 512
__launch_bounds__(SCAN_B)
__global__ void scan_partial_kernel(const int* __restrict__ cnt, int* __restrict__ bsum, int n) {
    __shared__ int sh[SCAN_B];
    int id = (int)(blockIdx.x * SCAN_B + threadIdx.x);
    sh[threadIdx.x] = (id < n) ? cnt[id] : 0;
    __syncthreads();
    for (int off = SCAN_B / 2; off > 0; off >>= 1) {
        if ((int)threadIdx.x < off) sh[threadIdx.x] += sh[threadIdx.x + off];
        __syncthreads();
    }
    if (threadIdx.x == 0) bsum[blockIdx.x] = sh[0];
}

__launch_bounds__(256)
__global__ void scan_base_kernel(const int* __restrict__ bsum, int* __restrict__ bbase,
                                 int* __restrict__ offs, int nblk, int nNodes) {
    __shared__ int sh[256];
    const int t = (int)threadIdx.x;
    int v = (t < nblk) ? bsum[t] : 0;
    sh[t] = v;
    __syncthreads();
    for (int off = 1; off < 256; off <<= 1) {
        int tmp = (t >= off) ? sh[t - off] : 0;
        __syncthreads();
        sh[t] += tmp;
        __syncthreads();
    }
    if (t < nblk) bbase[t] = sh[t] - v;       // exclusive base per block
    if (t == 255) offs[nNodes] = sh[255];     // grand total
}

__launch_bounds__(SCAN_B)
__global__ void scan_final_kernel(int* __restrict__ cnt, const int* __restrict__ bbase,
                                  int* __restrict__ offs, int n) {
    __shared__ int sh[SCAN_B];
    int id = (int)(blockIdx.x * SCAN_B + threadIdx.x);
    int v = (id < n) ? cnt[id] : 0;
    sh[threadIdx.x] = v;
    __syncthreads();
    for (int off = 1; off < SCAN_B; off <<= 1) {
        int tmp = ((int)threadIdx.x >= off) ? sh[threadIdx.x - off] : 0;
        __syncthreads();
        sh[threadIdx.x] += tmp;
        __syncthreads();
    }
    if (id < n) {
        int excl = sh[threadIdx.x] - v + bbase[blockIdx.x];
        offs[id] = excl;
        cnt[id]  = excl;   // becomes the scatter cursor
    }
}

__global__ void scatter_kernel(const int* __restrict__ src, const int* __restrict__ dst,
                               const int* __restrict__ et, const float* __restrict__ norm,
                               int* __restrict__ cursor, uint2* __restrict__ rec, int nE) {
    for (int e = (int)(blockIdx.x * blockDim.x + threadIdx.x); e < nE;
         e += (int)(gridDim.x * blockDim.x)) {
        int p = atomicAdd(&cursor[dst[e]], 1);
        rec[p] = make_uint2((uint32_t)src[e] | ((uint32_t)et[e] << 20), asu(norm[e]));
    }
}

// ---------------------------------------------------------------------------
// Input-space aggregation: G[d][i][b] = sum_{e in in(d)} norm_e*coeff[r_e,b]*x[src_e,i]
// HALF-WAVE per dst node; unroll-8 => 16 independent x-gathers per wave in
// flight (latency hiding). coeff staged in LDS (2.8 KB, broadcast reads) so
// VMEM slots carry only rec + x. Edge order and FMA order per (i,b) identical
// to the proven kernel -> bit-identical G.
// ---------------------------------------------------------------------------
__launch_bounds__(256)
__global__ void csr_agg_kernel(const uint16_t* __restrict__ x,
                               const float* __restrict__ coeff,
                               const int* __restrict__ offs,
                               const uint2* __restrict__ rec,
                               uint16_t* __restrict__ G, int nNodes) {
    __shared__ __align__(16) float cS[NREL * NB];   // 2880 B
    for (int i = (int)threadIdx.x; i < NREL * NB; i += 256) cS[i] = coeff[i];
    __syncthreads();

    const int hl   = (int)threadIdx.x & 31;   // lane within half-wave
    const int hwid = (int)((blockIdx.x * blockDim.x + threadIdx.x) >> 5);
    const int nhw  = (int)((gridDim.x * blockDim.x) >> 5);

    for (int d = hwid; d < nNodes; d += nhw) {
        const int j0 = offs[d], j1 = offs[d + 1];
        float accL[NB] = {0.f, 0.f, 0.f, 0.f, 0.f, 0.f, 0.f, 0.f};  // i = 2*hl
        float accH[NB] = {0.f, 0.f, 0.f, 0.f, 0.f, 0.f, 0.f, 0.f};  // i = 2*hl+1
        int j = j0;
        for (; j + 8 <= j1; j += 8) {
            uint2 r[8];
#pragma unroll
            for (int u = 0; u < 8; u++) r[u] = rec[j + u];
            uint32_t w[8];
#pragma unroll
            for (int u = 0; u < 8; u++)
                w[u] = *reinterpret_cast<const uint32_t*>(
                    x + (size_t)(r[u].x & 0xFFFFFu) * HDIM + 2 * hl);
#pragma unroll
            for (int u = 0; u < 8; u++) {
                const float4 cA = *reinterpret_cast<const float4*>(cS + (r[u].x >> 20) * NB);
                const float4 cB = *reinterpret_cast<const float4*>(cS + (r[u].x >> 20) * NB + 4);
                const float nm = asf(r[u].y);
                fmaC(cA, cB, asf(w[u] << 16) * nm, accL);
                fmaC(cA, cB, asf(w[u] & 0xFFFF0000u) * nm, accH);
            }
        }
        for (; j < j1; j++) {
            const uint2 r0 = rec[j];
            const uint32_t w0 = *reinterpret_cast<const uint32_t*>(
                x + (size_t)(r0.x & 0xFFFFFu) * HDIM + 2 * hl);
            const float4 cA = *reinterpret_cast<const float4*>(cS + (r0.x >> 20) * NB);
            const float4 cB = *reinterpret_cast<const float4*>(cS + (r0.x >> 20) * NB + 4);
            const float nm = asf(r0.y);
            fmaC(cA, cB, asf(w0 << 16) * nm, accL);
            fmaC(cA, cB, asf(w0 & 0xFFFF0000u) * nm, accH);
        }
        // lane hl owns k = 16*hl .. 16*hl+15 (i=2hl -> b0..7, i=2hl+1 -> b0..7)
        uint4 lo, hi;
        lo.x = pack2(accL[0], accL[1]); lo.y = pack2(accL[2], accL[3]);
        lo.z = pack2(accL[4], accL[5]); lo.w = pack2(accL[6], accL[7]);
        hi.x = pack2(accH[0], accH[1]); hi.y = pack2(accH[2], accH[3]);
        hi.z = pack2(accH[4], accH[5]); hi.w = pack2(accH[6], accH[7]);
        uint16_t* gp = G + (size_t)d * KDIM + hl * 16;
        *reinterpret_cast<uint4*>(gp)     = lo;
        *reinterpret_cast<uint4*>(gp + 8) = hi;
    }
}

// ---------------------------------------------------------------------------
// MFMA GEMM: [N,512] bf16 (G) x [512,DOUT] bf16 (Wf swizzled in LDS).
// 1024-thread blocks: 16 waves share ONE 64 KB Wf copy -> 2 blocks/CU =
// 32 waves/CU (was 8). Per-wave inner loop identical to the proven proj:
// wave w owns 16 nodes (tile of 256 nodes per block), A-frag reused across
// the 4 o-tiles. mfma_f32_16x16x32_bf16 layout as before.
// ---------------------------------------------------------------------------
__launch_bounds__(1024)
__global__ void proj_hidden_kernel(const uint16_t* __restrict__ G,
                                   const float* __restrict__ bases,
                                   const float* __restrict__ bias,
                                   uint16_t* __restrict__ xout, int nNodes) {
    constexpr int OT = HDIM / 16;       // 4 o-tiles
    __shared__ __align__(16) uint16_t Wf[16 * OT * 64 * 8];   // 64 KB

    const int t    = (int)threadIdx.x;
    const int lane = t & 63;
    const int w    = t >> 6;            // 0..15
    const int q    = lane >> 4;
    const int c    = lane & 15;

    for (int idx = t; idx < 16 * OT * 64 * 8; idx += 1024) {
        int j    = idx & 7;
        int ln   = (idx >> 3) & 63;
        int rest = idx >> 9;            // kb*OT + ot
        int ot   = rest & (OT - 1);
        int kb   = rest >> 2;
        int k    = kb * 32 + (ln >> 4) * 8 + j;
        int o    = ot * 16 + (ln & 15);
        int i    = k >> 3, b = k & 7;
        Wf[idx] = f2bf(bases[(size_t)(b * HDIM + i) * HDIM + o]);
    }
    __syncthreads();

    float bv[OT];
#pragma unroll
    for (int ot = 0; ot < OT; ot++) bv[ot] = bias[ot * 16 + c];

    const int nTiles = (nNodes + 255) / 256;
    for (int tile = (int)blockIdx.x; tile < nTiles; tile += (int)gridDim.x) {
        const int n0w = tile * 256 + w * 16;
        int arow = n0w + c;
        if (arow > nNodes - 1) arow = nNodes - 1;
        const uint16_t* gp = G + (size_t)arow * KDIM + q * 8;

        f32x4 acc[OT];
#pragma unroll
        for (int ot = 0; ot < OT; ot++) acc[ot] = {0.f, 0.f, 0.f, 0.f};

#pragma unroll
        for (int kb = 0; kb < 16; kb++) {
            FragU a;
            a.u = *reinterpret_cast<const uint4*>(gp + kb * 32);
#pragma unroll
            for (int ot = 0; ot < OT; ot++) {
                FragU b;
                b.u = *reinterpret_cast<const uint4*>(Wf + ((kb * OT + ot) * 64 + lane) * 8);
                acc[ot] = __builtin_amdgcn_mfma_f32_16x16x32_bf16(a.s, b.s, acc[ot], 0, 0, 0);
            }
        }

#pragma unroll
        for (int r = 0; r < 4; r++) {
            const int node = n0w + q * 4 + r;
            if (node < nNodes) {
#pragma unroll
                for (int ot = 0; ot < OT; ot++) {
                    float v = fmaxf(acc[ot][r] + bv[ot], 0.f);
                    xout[(size_t)node * HDIM + ot * 16 + c] = f2bf(v);
                }
            }
        }
    }
}

__launch_bounds__(1024)
__global__ void proj_out_kernel(const uint16_t* __restrict__ G,
                                const float* __restrict__ bases,
                                const float* __restrict__ bias,
                                float* __restrict__ out, int nNodes) {
    __shared__ __align__(16) uint16_t Wf[16 * 64 * 8];   // 16 KB

    const int t    = (int)threadIdx.x;
    const int lane = t & 63;
    const int w    = t >> 6;
    const int q    = lane >> 4;
    const int c    = lane & 15;

    for (int idx = t; idx < 16 * 64 * 8; idx += 1024) {
        int j  = idx & 7;
        int ln = (idx >> 3) & 63;
        int kb = idx >> 9;
        int k  = kb * 32 + (ln >> 4) * 8 + j;
        int o  = ln & 15;
        int i  = k >> 3, b = k & 7;
        Wf[idx] = f2bf(bases[(size_t)(b * HDIM + i) * ODIM + o]);
    }
    __syncthreads();

    const float bv = bias[c];

    const int nTiles = (nNodes + 255) / 256;
    for (int tile = (int)blockIdx.x; tile < nTiles; tile += (int)gridDim.x) {
        const int n0w = tile * 256 + w * 16;
        int arow = n0w + c;
        if (arow > nNodes - 1) arow = nNodes - 1;
        const uint16_t* gp = G + (size_t)arow * KDIM + q * 8;

        f32x4 acc = {0.f, 0.f, 0.f, 0.f};
#pragma unroll
        for (int kb = 0; kb < 16; kb++) {
            FragU a, b;
            a.u = *reinterpret_cast<const uint4*>(gp + kb * 32);
            b.u = *reinterpret_cast<const uint4*>(Wf + (kb * 64 + lane) * 8);
            acc = __builtin_amdgcn_mfma_f32_16x16x32_bf16(a.s, b.s, acc, 0, 0, 0);
        }

#pragma unroll
        for (int r = 0; r < 4; r++) {
            const int node = n0w + q * 4 + r;
            if (node < nNodes) out[(size_t)node * ODIM + c] = acc[r] + bv;
        }
    }
}

extern "C" void kernel_launch(void* const* d_in, const int* in_sizes, int n_in,
                              void* d_out, int out_size, void* d_ws, size_t ws_size,
                              hipStream_t stream) {
    const float* feats  = (const float*)d_in[0];
    const float* coeff0 = (const float*)d_in[1];
    const float* bases0 = (const float*)d_in[2];
    const float* bias0  = (const float*)d_in[3];
    const float* coeff1 = (const float*)d_in[4];
    const float* bases1 = (const float*)d_in[5];
    const float* bias1  = (const float*)d_in[6];
    const float* coeff2 = (const float*)d_in[7];
    const float* bases2 = (const float*)d_in[8];
    const float* bias2  = (const float*)d_in[9];
    const int*   src    = (const int*)d_in[10];
    const int*   dst    = (const int*)d_in[11];
    const int*   etype  = (const int*)d_in[12];
    const float* norm   = (const float*)d_in[13];
    float* out = (float*)d_out;

    char* base = (char*)d_ws;
    // layout: G 102.4MB | x 12.8MB | offs | cursor | bsum | bbase | rec 8MB
    uint16_t* G = (uint16_t*)base;
    uint16_t* x = (uint16_t*)(base + (size_t)NNODES * KDIM * 2);       // +102,400,000
    const size_t OFF_OFFS  = 115200000;
    const size_t OFF_CURS  = OFF_OFFS + 400016;
    const size_t OFF_BSUM  = OFF_CURS + 400016;
    const size_t OFF_BBASE = OFF_BSUM + 1024;
    const size_t OFF_REC   = OFF_BBASE + 1024;                         // 116,002,080
    int*   offs  = (int*)(base + OFF_OFFS);
    int*   curs  = (int*)(base + OFF_CURS);
    int*   bsum  = (int*)(base + OFF_BSUM);
    int*   bbase = (int*)(base + OFF_BBASE);
    uint2* rec   = (uint2*)(base + OFF_REC);

    const int nblk = (NNODES + SCAN_B - 1) / SCAN_B;   // 196 <= 256

    // ---- CSR build (graph identical across layers; built once per call)
    hipLaunchKernelGGL(zero_kernel, dim3(256), dim3(256), 0, stream, curs, NNODES);
    hipLaunchKernelGGL(hist_kernel, dim3(2048), dim3(256), 0, stream, dst, curs, NEDGES);
    hipLaunchKernelGGL(scan_partial_kernel, dim3(nblk), dim3(SCAN_B), 0, stream, curs, bsum, NNODES);
    hipLaunchKernelGGL(scan_base_kernel, dim3(1), dim3(256), 0, stream, bsum, bbase, offs, nblk, NNODES);
    hipLaunchKernelGGL(scan_final_kernel, dim3(nblk), dim3(SCAN_B), 0, stream, curs, bbase, offs, NNODES);
    hipLaunchKernelGGL(scatter_kernel, dim3(2048), dim3(256), 0, stream,
                       src, dst, etype, norm, curs, rec, NEDGES);

    // ---- x0 = bf16(feats)
    hipLaunchKernelGGL(cast_kernel, dim3(2048), dim3(256), 0, stream,
                       feats, x, NNODES * HDIM / 4);

    // ---- Layer 0
    hipLaunchKernelGGL(csr_agg_kernel, dim3(2048), dim3(256), 0, stream,
                       x, coeff0, offs, rec, G, NNODES);
    hipLaunchKernelGGL(proj_hidden_kernel, dim3(512), dim3(1024), 0, stream,
                       G, bases0, bias0, x, NNODES);
    // ---- Layer 1
    hipLaunchKernelGGL(csr_agg_kernel, dim3(2048), dim3(256), 0, stream,
                       x, coeff1, offs, rec, G, NNODES);
    hipLaunchKernelGGL(proj_hidden_kernel, dim3(512), dim3(1024), 0, stream,
                       G, bases1, bias1, x, NNODES);
    // ---- Layer 2
    hipLaunchKernelGGL(csr_agg_kernel, dim3(2048), dim3(256), 0, stream,
                       x, coeff2, offs, rec, G, NNODES);
    hipLaunchKernelGGL(proj_out_kernel, dim3(512), dim3(1024), 0, stream,
                       G, bases2, bias2, out, NNODES);
}

// Round 7
// 553.535 us; speedup vs baseline: 1.3079x; 1.3079x over previous
//
#include <hip/hip_runtime.h>
#include <hip/hip_bf16.h>
#include <cstdint>

#define NNODES 100000
#define NEDGES 1000000
#define HDIM 64
#define ODIM 16
#define NB 8
#define NREL 90
#define KDIM (HDIM * NB)   // 512 = GEMM inner dim, k = i*8 + b

typedef short short8 __attribute__((ext_vector_type(8)));
typedef float f32x4  __attribute__((ext_vector_type(4)));
union FragU { uint4 u; short8 s; };

__device__ __forceinline__ float asf(uint32_t u) { float f; __builtin_memcpy(&f, &u, 4); return f; }
__device__ __forceinline__ uint32_t asu(float f) { uint32_t u; __builtin_memcpy(&u, &f, 4); return u; }
__device__ __forceinline__ uint16_t f2bf(float f) {
    uint32_t x = asu(f);
    return (uint16_t)((x + 0x7FFFu + ((x >> 16) & 1u)) >> 16);
}
__device__ __forceinline__ uint32_t pack2(float lo, float hi) {
    return (uint32_t)f2bf(lo) | ((uint32_t)f2bf(hi) << 16);
}
__device__ __forceinline__ void fmaC(const float4& cA, const float4& cB, float xs,
                                     float* __restrict__ acc) {
    acc[0] = fmaf(cA.x, xs, acc[0]); acc[1] = fmaf(cA.y, xs, acc[1]);
    acc[2] = fmaf(cA.z, xs, acc[2]); acc[3] = fmaf(cA.w, xs, acc[3]);
    acc[4] = fmaf(cB.x, xs, acc[4]); acc[5] = fmaf(cB.y, xs, acc[5]);
    acc[6] = fmaf(cB.z, xs, acc[6]); acc[7] = fmaf(cB.w, xs, acc[7]);
}

// ---------------------------------------------------------------------------
// cast: f32 feats -> bf16 x  (4 elems/thread)
// ---------------------------------------------------------------------------
__global__ void cast_kernel(const float* __restrict__ in, uint16_t* __restrict__ out, int n4) {
    const int stride = (int)(gridDim.x * blockDim.x);
    for (int idx = (int)(blockIdx.x * blockDim.x + threadIdx.x); idx < n4; idx += stride) {
        float4 v = reinterpret_cast<const float4*>(in)[idx];
        uint2 p;
        p.x = pack2(v.x, v.y);
        p.y = pack2(v.z, v.w);
        reinterpret_cast<uint2*>(out)[idx] = p;
    }
}

// ---------------------------------------------------------------------------
// CSR build: histogram by dst -> exclusive scan -> scatter packed edge recs
// rec[e] = { src | (etype<<20), norm }  (8 B)
// ---------------------------------------------------------------------------
__global__ void zero_kernel(int* __restrict__ p, int n) {
    for (int i = (int)(blockIdx.x * blockDim.x + threadIdx.x); i < n;
         i += (int)(gridDim.x * blockDim.x)) p[i] = 0;
}

__global__ void hist_kernel(const int* __restrict__ dst, int* __restrict__ cnt, int nE) {
    for (int e = (int)(blockIdx.x * blockDim.x + threadIdx.x); e < nE;
         e += (int)(gridDim.x * blockDim.x)) atomicAdd(&cnt[dst[e]], 1);
}

#define SCAN_B 512
__launch_bounds__(SCAN_B)
__global__ void scan_partial_kernel(const int* __restrict__ cnt, int* __restrict__ bsum, int n) {
    __shared__ int sh[SCAN_B];
    int id = (int)(blockIdx.x * SCAN_B + threadIdx.x);
    sh[threadIdx.x] = (id < n) ? cnt[id] : 0;
    __syncthreads();
    for (int off = SCAN_B / 2; off > 0; off >>= 1) {
        if ((int)threadIdx.x < off) sh[threadIdx.x] += sh[threadIdx.x + off];
        __syncthreads();
    }
    if (threadIdx.x == 0) bsum[blockIdx.x] = sh[0];
}

__launch_bounds__(256)
__global__ void scan_base_kernel(const int* __restrict__ bsum, int* __restrict__ bbase,
                                 int* __restrict__ offs, int nblk, int nNodes) {
    __shared__ int sh[256];
    const int t = (int)threadIdx.x;
    int v = (t < nblk) ? bsum[t] : 0;
    sh[t] = v;
    __syncthreads();
    for (int off = 1; off < 256; off <<= 1) {
        int tmp = (t >= off) ? sh[t - off] : 0;
        __syncthreads();
        sh[t] += tmp;
        __syncthreads();
    }
    if (t < nblk) bbase[t] = sh[t] - v;       // exclusive base per block
    if (t == 255) offs[nNodes] = sh[255];     // grand total
}

__launch_bounds__(SCAN_B)
__global__ void scan_final_kernel(int* __restrict__ cnt, const int* __restrict__ bbase,
                                  int* __restrict__ offs, int n) {
    __shared__ int sh[SCAN_B];
    int id = (int)(blockIdx.x * SCAN_B + threadIdx.x);
    int v = (id < n) ? cnt[id] : 0;
    sh[threadIdx.x] = v;
    __syncthreads();
    for (int off = 1; off < SCAN_B; off <<= 1) {
        int tmp = ((int)threadIdx.x >= off) ? sh[threadIdx.x - off] : 0;
        __syncthreads();
        sh[threadIdx.x] += tmp;
        __syncthreads();
    }
    if (id < n) {
        int excl = sh[threadIdx.x] - v + bbase[blockIdx.x];
        offs[id] = excl;
        cnt[id]  = excl;   // becomes the scatter cursor
    }
}

__global__ void scatter_kernel(const int* __restrict__ src, const int* __restrict__ dst,
                               const int* __restrict__ et, const float* __restrict__ norm,
                               int* __restrict__ cursor, uint2* __restrict__ rec, int nE) {
    for (int e = (int)(blockIdx.x * blockDim.x + threadIdx.x); e < nE;
         e += (int)(gridDim.x * blockDim.x)) {
        int p = atomicAdd(&cursor[dst[e]], 1);
        rec[p] = make_uint2((uint32_t)src[e] | ((uint32_t)et[e] << 20), asu(norm[e]));
    }
}

// ---------------------------------------------------------------------------
// Input-space aggregation (EXACT round-0 measured form, 74.2 us):
// G[d][i][b] = sum_{e in in(d)} norm_e*coeff[r_e,b]*x[src_e,i]
// HALF-WAVE per dst node: lane hl covers i = 2*hl, 2*hl+1 via one dword load.
// Two nodes per wave + unroll-4 = 8 independent gather chains in flight.
// ---------------------------------------------------------------------------
__launch_bounds__(256)
__global__ void csr_agg_kernel(const uint16_t* __restrict__ x,
                               const float* __restrict__ coeff,
                               const int* __restrict__ offs,
                               const uint2* __restrict__ rec,
                               uint16_t* __restrict__ G, int nNodes) {
    const int hl   = (int)threadIdx.x & 31;   // lane within half-wave
    const int hwid = (int)((blockIdx.x * blockDim.x + threadIdx.x) >> 5);
    const int nhw  = (int)((gridDim.x * blockDim.x) >> 5);
    for (int d = hwid; d < nNodes; d += nhw) {
        const int j0 = offs[d], j1 = offs[d + 1];
        float accL[NB] = {0.f, 0.f, 0.f, 0.f, 0.f, 0.f, 0.f, 0.f};  // i = 2*hl
        float accH[NB] = {0.f, 0.f, 0.f, 0.f, 0.f, 0.f, 0.f, 0.f};  // i = 2*hl+1
        int j = j0;
        for (; j + 4 <= j1; j += 4) {
            const uint2 r0 = rec[j];
            const uint2 r1 = rec[j + 1];
            const uint2 r2 = rec[j + 2];
            const uint2 r3 = rec[j + 3];
            const uint32_t w0 = *reinterpret_cast<const uint32_t*>(
                x + (size_t)(r0.x & 0xFFFFFu) * HDIM + 2 * hl);
            const uint32_t w1 = *reinterpret_cast<const uint32_t*>(
                x + (size_t)(r1.x & 0xFFFFFu) * HDIM + 2 * hl);
            const uint32_t w2 = *reinterpret_cast<const uint32_t*>(
                x + (size_t)(r2.x & 0xFFFFFu) * HDIM + 2 * hl);
            const uint32_t w3 = *reinterpret_cast<const uint32_t*>(
                x + (size_t)(r3.x & 0xFFFFFu) * HDIM + 2 * hl);

            {
                const float4 cA = *reinterpret_cast<const float4*>(coeff + (r0.x >> 20) * NB);
                const float4 cB = *reinterpret_cast<const float4*>(coeff + (r0.x >> 20) * NB + 4);
                const float nm = asf(r0.y);
                fmaC(cA, cB, asf(w0 << 16) * nm, accL);
                fmaC(cA, cB, asf(w0 & 0xFFFF0000u) * nm, accH);
            }
            {
                const float4 cA = *reinterpret_cast<const float4*>(coeff + (r1.x >> 20) * NB);
                const float4 cB = *reinterpret_cast<const float4*>(coeff + (r1.x >> 20) * NB + 4);
                const float nm = asf(r1.y);
                fmaC(cA, cB, asf(w1 << 16) * nm, accL);
                fmaC(cA, cB, asf(w1 & 0xFFFF0000u) * nm, accH);
            }
            {
                const float4 cA = *reinterpret_cast<const float4*>(coeff + (r2.x >> 20) * NB);
                const float4 cB = *reinterpret_cast<const float4*>(coeff + (r2.x >> 20) * NB + 4);
                const float nm = asf(r2.y);
                fmaC(cA, cB, asf(w2 << 16) * nm, accL);
                fmaC(cA, cB, asf(w2 & 0xFFFF0000u) * nm, accH);
            }
            {
                const float4 cA = *reinterpret_cast<const float4*>(coeff + (r3.x >> 20) * NB);
                const float4 cB = *reinterpret_cast<const float4*>(coeff + (r3.x >> 20) * NB + 4);
                const float nm = asf(r3.y);
                fmaC(cA, cB, asf(w3 << 16) * nm, accL);
                fmaC(cA, cB, asf(w3 & 0xFFFF0000u) * nm, accH);
            }
        }
        for (; j < j1; j++) {
            const uint2 r0 = rec[j];
            const uint32_t w0 = *reinterpret_cast<const uint32_t*>(
                x + (size_t)(r0.x & 0xFFFFFu) * HDIM + 2 * hl);
            const float4 cA = *reinterpret_cast<const float4*>(coeff + (r0.x >> 20) * NB);
            const float4 cB = *reinterpret_cast<const float4*>(coeff + (r0.x >> 20) * NB + 4);
            const float nm = asf(r0.y);
            fmaC(cA, cB, asf(w0 << 16) * nm, accL);
            fmaC(cA, cB, asf(w0 & 0xFFFF0000u) * nm, accH);
        }
        // lane hl owns k = 16*hl .. 16*hl+15 (i=2hl -> b0..7, i=2hl+1 -> b0..7)
        uint4 lo, hi;
        lo.x = pack2(accL[0], accL[1]); lo.y = pack2(accL[2], accL[3]);
        lo.z = pack2(accL[4], accL[5]); lo.w = pack2(accL[6], accL[7]);
        hi.x = pack2(accH[0], accH[1]); hi.y = pack2(accH[2], accH[3]);
        hi.z = pack2(accH[4], accH[5]); hi.w = pack2(accH[6], accH[7]);
        uint16_t* gp = G + (size_t)d * KDIM + hl * 16;
        *reinterpret_cast<uint4*>(gp)     = lo;
        *reinterpret_cast<uint4*>(gp + 8) = hi;
    }
}

// ---------------------------------------------------------------------------
// MFMA GEMM with REGISTER-resident B-panel (no LDS, no barriers, no spill):
// At HDIM=64 one o-tile's weight panel is 512x16 bf16 = 64 VGPR/lane (16
// frags of 4 regs). 256-thread blocks; wave w owns o-tile w, builds its
// B-frags from bases once, then streams G: 1 x 16B a-load + 1 MFMA per kb.
// B-frag element (kb, q, j) = Wf[k=kb*32+q*8+j][ot*16+c] -- identical values
// and MFMA order to the proven LDS version -> bit-identical output.
// launch_bounds(256,3): VGPR cap ~168 (need ~120), >=12 waves/CU.
// ---------------------------------------------------------------------------
__launch_bounds__(256, 3)
__global__ void proj_hidden_kernel(const uint16_t* __restrict__ G,
                                   const float* __restrict__ bases,
                                   const float* __restrict__ bias,
                                   uint16_t* __restrict__ xout, int nNodes) {
    const int t    = (int)threadIdx.x;
    const int lane = t & 63;
    const int ot   = t >> 6;            // wave = o-tile (0..3)
    const int q    = lane >> 4;
    const int c    = lane & 15;

    FragU bf[16];
#pragma unroll
    for (int kb = 0; kb < 16; kb++) {
#pragma unroll
        for (int j = 0; j < 8; j++) {
            const int k = kb * 32 + q * 8 + j;
            const int i = k >> 3, b = k & 7;
            bf[kb].s[j] = (short)f2bf(bases[(size_t)(b * HDIM + i) * HDIM + ot * 16 + c]);
        }
    }
    const float bv = bias[ot * 16 + c];

    const int nTiles = (nNodes + 63) / 64;
    for (int tile = (int)blockIdx.x; tile < nTiles; tile += (int)gridDim.x) {
#pragma unroll
        for (int g = 0; g < 4; g++) {
            int arow = tile * 64 + g * 16 + c;
            if (arow > nNodes - 1) arow = nNodes - 1;
            const uint16_t* gp = G + (size_t)arow * KDIM + q * 8;

            f32x4 acc = {0.f, 0.f, 0.f, 0.f};
#pragma unroll
            for (int kb = 0; kb < 16; kb++) {
                FragU a;
                a.u = *reinterpret_cast<const uint4*>(gp + kb * 32);
                acc = __builtin_amdgcn_mfma_f32_16x16x32_bf16(a.s, bf[kb].s, acc, 0, 0, 0);
            }

            const int nbase = tile * 64 + g * 16 + q * 4;
#pragma unroll
            for (int r = 0; r < 4; r++) {
                const int node = nbase + r;
                if (node < nNodes) {
                    float v = fmaxf(acc[r] + bv, 0.f);
                    xout[(size_t)node * HDIM + ot * 16 + c] = f2bf(v);
                }
            }
        }
    }
}

__launch_bounds__(256, 3)
__global__ void proj_out_kernel(const uint16_t* __restrict__ G,
                                const float* __restrict__ bases,
                                const float* __restrict__ bias,
                                float* __restrict__ out, int nNodes) {
    const int t    = (int)threadIdx.x;
    const int lane = t & 63;
    const int w    = t >> 6;            // wave = node-group (0..3), single o-tile
    const int q    = lane >> 4;
    const int c    = lane & 15;

    FragU bf[16];
#pragma unroll
    for (int kb = 0; kb < 16; kb++) {
#pragma unroll
        for (int j = 0; j < 8; j++) {
            const int k = kb * 32 + q * 8 + j;
            const int i = k >> 3, b = k & 7;
            bf[kb].s[j] = (short)f2bf(bases[(size_t)(b * HDIM + i) * ODIM + c]);
        }
    }
    const float bv = bias[c];

    const int nTiles = (nNodes + 63) / 64;
    for (int tile = (int)blockIdx.x; tile < nTiles; tile += (int)gridDim.x) {
        int arow = tile * 64 + w * 16 + c;
        if (arow > nNodes - 1) arow = nNodes - 1;
        const uint16_t* gp = G + (size_t)arow * KDIM + q * 8;

        f32x4 acc = {0.f, 0.f, 0.f, 0.f};
#pragma unroll
        for (int kb = 0; kb < 16; kb++) {
            FragU a;
            a.u = *reinterpret_cast<const uint4*>(gp + kb * 32);
            acc = __builtin_amdgcn_mfma_f32_16x16x32_bf16(a.s, bf[kb].s, acc, 0, 0, 0);
        }

        const int nbase = tile * 64 + w * 16 + q * 4;
#pragma unroll
        for (int r = 0; r < 4; r++) {
            const int node = nbase + r;
            if (node < nNodes) out[(size_t)node * ODIM + c] = acc[r] + bv;
        }
    }
}

extern "C" void kernel_launch(void* const* d_in, const int* in_sizes, int n_in,
                              void* d_out, int out_size, void* d_ws, size_t ws_size,
                              hipStream_t stream) {
    const float* feats  = (const float*)d_in[0];
    const float* coeff0 = (const float*)d_in[1];
    const float* bases0 = (const float*)d_in[2];
    const float* bias0  = (const float*)d_in[3];
    const float* coeff1 = (const float*)d_in[4];
    const float* bases1 = (const float*)d_in[5];
    const float* bias1  = (const float*)d_in[6];
    const float* coeff2 = (const float*)d_in[7];
    const float* bases2 = (const float*)d_in[8];
    const float* bias2  = (const float*)d_in[9];
    const int*   src    = (const int*)d_in[10];
    const int*   dst    = (const int*)d_in[11];
    const int*   etype  = (const int*)d_in[12];
    const float* norm   = (const float*)d_in[13];
    float* out = (float*)d_out;

    char* base = (char*)d_ws;
    // layout: G 102.4MB | x 12.8MB | offs | cursor | bsum | bbase | rec 8MB
    uint16_t* G = (uint16_t*)base;
    uint16_t* x = (uint16_t*)(base + (size_t)NNODES * KDIM * 2);       // +102,400,000
    const size_t OFF_OFFS  = 115200000;
    const size_t OFF_CURS  = OFF_OFFS + 400016;
    const size_t OFF_BSUM  = OFF_CURS + 400016;
    const size_t OFF_BBASE = OFF_BSUM + 1024;
    const size_t OFF_REC   = OFF_BBASE + 1024;                         // 116,002,080
    int*   offs  = (int*)(base + OFF_OFFS);
    int*   curs  = (int*)(base + OFF_CURS);
    int*   bsum  = (int*)(base + OFF_BSUM);
    int*   bbase = (int*)(base + OFF_BBASE);
    uint2* rec   = (uint2*)(base + OFF_REC);

    const int nblk = (NNODES + SCAN_B - 1) / SCAN_B;   // 196 <= 256

    // ---- CSR build (graph identical across layers; built once per call)
    hipLaunchKernelGGL(zero_kernel, dim3(256), dim3(256), 0, stream, curs, NNODES);
    hipLaunchKernelGGL(hist_kernel, dim3(2048), dim3(256), 0, stream, dst, curs, NEDGES);
    hipLaunchKernelGGL(scan_partial_kernel, dim3(nblk), dim3(SCAN_B), 0, stream, curs, bsum, NNODES);
    hipLaunchKernelGGL(scan_base_kernel, dim3(1), dim3(256), 0, stream, bsum, bbase, offs, nblk, NNODES);
    hipLaunchKernelGGL(scan_final_kernel, dim3(nblk), dim3(SCAN_B), 0, stream, curs, bbase, offs, NNODES);
    hipLaunchKernelGGL(scatter_kernel, dim3(2048), dim3(256), 0, stream,
                       src, dst, etype, norm, curs, rec, NEDGES);

    // ---- x0 = bf16(feats)
    hipLaunchKernelGGL(cast_kernel, dim3(2048), dim3(256), 0, stream,
                       feats, x, NNODES * HDIM / 4);

    // ---- Layer 0
    hipLaunchKernelGGL(csr_agg_kernel, dim3(2048), dim3(256), 0, stream,
                       x, coeff0, offs, rec, G, NNODES);
    hipLaunchKernelGGL(proj_hidden_kernel, dim3(1024), dim3(256), 0, stream,
                       G, bases0, bias0, x, NNODES);
    // ---- Layer 1
    hipLaunchKernelGGL(csr_agg_kernel, dim3(2048), dim3(256), 0, stream,
                       x, coeff1, offs, rec, G, NNODES);
    hipLaunchKernelGGL(proj_hidden_kernel, dim3(1024), dim3(256), 0, stream,
                       G, bases1, bias1, x, NNODES);
    // ---- Layer 2
    hipLaunchKernelGGL(csr_agg_kernel, dim3(2048), dim3(256), 0, stream,
                       x, coeff2, offs, rec, G, NNODES);
    hipLaunchKernelGGL(proj_out_kernel, dim3(1024), dim3(256), 0, stream,
                       G, bases2, bias2, out, NNODES);
}

// Round 10
// 498.224 us; speedup vs baseline: 1.4531x; 1.1110x over previous
//
#include <hip/hip_runtime.h>
#include <hip/hip_bf16.h>
#include <cstdint>

#define NNODES 100000
#define NEDGES 1000000
#define HDIM 64
#define ODIM 16
#define NB 8
#define NREL 90
#define KDIM (HDIM * NB)   // 512 = GEMM inner dim, k = i*8 + b

typedef short short8 __attribute__((ext_vector_type(8)));
typedef float f32x4  __attribute__((ext_vector_type(4)));
union FragU { uint4 u; short8 s; };

__device__ __forceinline__ float asf(uint32_t u) { float f; __builtin_memcpy(&f, &u, 4); return f; }
__device__ __forceinline__ uint32_t asu(float f) { uint32_t u; __builtin_memcpy(&u, &f, 4); return u; }
__device__ __forceinline__ uint16_t f2bf(float f) {
    uint32_t x = asu(f);
    return (uint16_t)((x + 0x7FFFu + ((x >> 16) & 1u)) >> 16);
}
__device__ __forceinline__ uint32_t pack2(float lo, float hi) {
    return (uint32_t)f2bf(lo) | ((uint32_t)f2bf(hi) << 16);
}
__device__ __forceinline__ void fmaC(const float4& cA, const float4& cB, float xs,
                                     float* __restrict__ acc) {
    acc[0] = fmaf(cA.x, xs, acc[0]); acc[1] = fmaf(cA.y, xs, acc[1]);
    acc[2] = fmaf(cA.z, xs, acc[2]); acc[3] = fmaf(cA.w, xs, acc[3]);
    acc[4] = fmaf(cB.x, xs, acc[4]); acc[5] = fmaf(cB.y, xs, acc[5]);
    acc[6] = fmaf(cB.z, xs, acc[6]); acc[7] = fmaf(cB.w, xs, acc[7]);
}

// ---------------------------------------------------------------------------
// cast: f32 feats -> bf16 x  (4 elems/thread)
// ---------------------------------------------------------------------------
__global__ void cast_kernel(const float* __restrict__ in, uint16_t* __restrict__ out, int n4) {
    const int stride = (int)(gridDim.x * blockDim.x);
    for (int idx = (int)(blockIdx.x * blockDim.x + threadIdx.x); idx < n4; idx += stride) {
        float4 v = reinterpret_cast<const float4*>(in)[idx];
        uint2 p;
        p.x = pack2(v.x, v.y);
        p.y = pack2(v.z, v.w);
        reinterpret_cast<uint2*>(out)[idx] = p;
    }
}

// ---------------------------------------------------------------------------
// CSR build: histogram by dst -> exclusive scan -> scatter packed edge recs
// rec[e] = { src | (etype<<20), norm }  (8 B)
// ---------------------------------------------------------------------------
__global__ void zero_kernel(int* __restrict__ p, int n) {
    for (int i = (int)(blockIdx.x * blockDim.x + threadIdx.x); i < n;
         i += (int)(gridDim.x * blockDim.x)) p[i] = 0;
}

__global__ void hist_kernel(const int* __restrict__ dst, int* __restrict__ cnt, int nE) {
    for (int e = (int)(blockIdx.x * blockDim.x + threadIdx.x); e < nE;
         e += (int)(gridDim.x * blockDim.x)) atomicAdd(&cnt[dst[e]], 1);
}

#define SCAN_B 512
__launch_bounds__(SCAN_B)
__global__ void scan_partial_kernel(const int* __restrict__ cnt, int* __restrict__ bsum, int n) {
    __shared__ int sh[SCAN_B];
    int id = (int)(blockIdx.x * SCAN_B + threadIdx.x);
    sh[threadIdx.x] = (id < n) ? cnt[id] : 0;
    __syncthreads();
    for (int off = SCAN_B / 2; off > 0; off >>= 1) {
        if ((int)threadIdx.x < off) sh[threadIdx.x] += sh[threadIdx.x + off];
        __syncthreads();
    }
    if (threadIdx.x == 0) bsum[blockIdx.x] = sh[0];
}

__launch_bounds__(256)
__global__ void scan_base_kernel(const int* __restrict__ bsum, int* __restrict__ bbase,
                                 int* __restrict__ offs, int nblk, int nNodes) {
    __shared__ int sh[256];
    const int t = (int)threadIdx.x;
    int v = (t < nblk) ? bsum[t] : 0;
    sh[t] = v;
    __syncthreads();
    for (int off = 1; off < 256; off <<= 1) {
        int tmp = (t >= off) ? sh[t - off] : 0;
        __syncthreads();
        sh[t] += tmp;
        __syncthreads();
    }
    if (t < nblk) bbase[t] = sh[t] - v;       // exclusive base per block
    if (t == 255) offs[nNodes] = sh[255];     // grand total
}

__launch_bounds__(SCAN_B)
__global__ void scan_final_kernel(int* __restrict__ cnt, const int* __restrict__ bbase,
                                  int* __restrict__ offs, int n) {
    __shared__ int sh[SCAN_B];
    int id = (int)(blockIdx.x * SCAN_B + threadIdx.x);
    int v = (id < n) ? cnt[id] : 0;
    sh[threadIdx.x] = v;
    __syncthreads();
    for (int off = 1; off < SCAN_B; off <<= 1) {
        int tmp = ((int)threadIdx.x >= off) ? sh[threadIdx.x - off] : 0;
        __syncthreads();
        sh[threadIdx.x] += tmp;
        __syncthreads();
    }
    if (id < n) {
        int excl = sh[threadIdx.x] - v + bbase[blockIdx.x];
        offs[id] = excl;
        cnt[id]  = excl;   // becomes the scatter cursor
    }
}

// ---------------------------------------------------------------------------
// Scatter, 4 edges per thread per iteration: vectorized int4/float4 edge
// loads, 4 INDEPENDENT atomicAdd chains in flight (was 1 -> latency-bound,
// VALUBusy 0.4%). rec content identical; within-dst order remains
// atomic-race-determined exactly as before.
// ---------------------------------------------------------------------------
__global__ void scatter_kernel(const int* __restrict__ src, const int* __restrict__ dst,
                               const int* __restrict__ et, const float* __restrict__ norm,
                               int* __restrict__ cursor, uint2* __restrict__ rec, int nE) {
    const int tid    = (int)(blockIdx.x * blockDim.x + threadIdx.x);
    const int stride = (int)(gridDim.x * blockDim.x);
    int e = tid * 4;
    for (; e + 4 <= nE; e += stride * 4) {
        const int4   d4 = *reinterpret_cast<const int4*>(dst + e);
        const int4   s4 = *reinterpret_cast<const int4*>(src + e);
        const int4   t4 = *reinterpret_cast<const int4*>(et + e);
        const float4 n4 = *reinterpret_cast<const float4*>(norm + e);
        const int p0 = atomicAdd(&cursor[d4.x], 1);
        const int p1 = atomicAdd(&cursor[d4.y], 1);
        const int p2 = atomicAdd(&cursor[d4.z], 1);
        const int p3 = atomicAdd(&cursor[d4.w], 1);
        rec[p0] = make_uint2((uint32_t)s4.x | ((uint32_t)t4.x << 20), asu(n4.x));
        rec[p1] = make_uint2((uint32_t)s4.y | ((uint32_t)t4.y << 20), asu(n4.y));
        rec[p2] = make_uint2((uint32_t)s4.z | ((uint32_t)t4.z << 20), asu(n4.z));
        rec[p3] = make_uint2((uint32_t)s4.w | ((uint32_t)t4.w << 20), asu(n4.w));
    }
    for (; e < nE; e++) {
        int p = atomicAdd(&cursor[dst[e]], 1);
        rec[p] = make_uint2((uint32_t)src[e] | ((uint32_t)et[e] << 20), asu(norm[e]));
    }
}

// ---------------------------------------------------------------------------
// Input-space aggregation: G[d][i][b] = sum_{e in in(d)} norm_e*coeff[r_e,b]*x[src_e,i]
// HALF-WAVE per dst node; unroll-8 => 16 independent x-gathers per wave in
// flight (was 8). coeff staged in LDS (2.8 KB, broadcast reads) so VMEM
// issue slots carry only rec + x. Edge order and FMA order per (i,b)
// identical to the measured round-0 kernel -> bit-identical G.
// ---------------------------------------------------------------------------
__launch_bounds__(256)
__global__ void csr_agg_kernel(const uint16_t* __restrict__ x,
                               const float* __restrict__ coeff,
                               const int* __restrict__ offs,
                               const uint2* __restrict__ rec,
                               uint16_t* __restrict__ G, int nNodes) {
    __shared__ __align__(16) float cS[NREL * NB];   // 2880 B
    for (int i = (int)threadIdx.x; i < NREL * NB; i += 256) cS[i] = coeff[i];
    __syncthreads();

    const int hl   = (int)threadIdx.x & 31;   // lane within half-wave
    const int hwid = (int)((blockIdx.x * blockDim.x + threadIdx.x) >> 5);
    const int nhw  = (int)((gridDim.x * blockDim.x) >> 5);

    for (int d = hwid; d < nNodes; d += nhw) {
        const int j0 = offs[d], j1 = offs[d + 1];
        float accL[NB] = {0.f, 0.f, 0.f, 0.f, 0.f, 0.f, 0.f, 0.f};  // i = 2*hl
        float accH[NB] = {0.f, 0.f, 0.f, 0.f, 0.f, 0.f, 0.f, 0.f};  // i = 2*hl+1
        int j = j0;
        for (; j + 8 <= j1; j += 8) {
            uint2 r[8];
#pragma unroll
            for (int u = 0; u < 8; u++) r[u] = rec[j + u];
            uint32_t w[8];
#pragma unroll
            for (int u = 0; u < 8; u++)
                w[u] = *reinterpret_cast<const uint32_t*>(
                    x + (size_t)(r[u].x & 0xFFFFFu) * HDIM + 2 * hl);
#pragma unroll
            for (int u = 0; u < 8; u++) {
                const float4 cA = *reinterpret_cast<const float4*>(cS + (r[u].x >> 20) * NB);
                const float4 cB = *reinterpret_cast<const float4*>(cS + (r[u].x >> 20) * NB + 4);
                const float nm = asf(r[u].y);
                fmaC(cA, cB, asf(w[u] << 16) * nm, accL);
                fmaC(cA, cB, asf(w[u] & 0xFFFF0000u) * nm, accH);
            }
        }
        for (; j < j1; j++) {
            const uint2 r0 = rec[j];
            const uint32_t w0 = *reinterpret_cast<const uint32_t*>(
                x + (size_t)(r0.x & 0xFFFFFu) * HDIM + 2 * hl);
            const float4 cA = *reinterpret_cast<const float4*>(cS + (r0.x >> 20) * NB);
            const float4 cB = *reinterpret_cast<const float4*>(cS + (r0.x >> 20) * NB + 4);
            const float nm = asf(r0.y);
            fmaC(cA, cB, asf(w0 << 16) * nm, accL);
            fmaC(cA, cB, asf(w0 & 0xFFFF0000u) * nm, accH);
        }
        // lane hl owns k = 16*hl .. 16*hl+15 (i=2hl -> b0..7, i=2hl+1 -> b0..7)
        uint4 lo, hi;
        lo.x = pack2(accL[0], accL[1]); lo.y = pack2(accL[2], accL[3]);
        lo.z = pack2(accL[4], accL[5]); lo.w = pack2(accL[6], accL[7]);
        hi.x = pack2(accH[0], accH[1]); hi.y = pack2(accH[2], accH[3]);
        hi.z = pack2(accH[4], accH[5]); hi.w = pack2(accH[6], accH[7]);
        uint16_t* gp = G + (size_t)d * KDIM + hl * 16;
        *reinterpret_cast<uint4*>(gp)     = lo;
        *reinterpret_cast<uint4*>(gp + 8) = hi;
    }
}

// ---------------------------------------------------------------------------
// MFMA GEMM with REGISTER-resident B-panel (measured good in round 7):
// 512x16 bf16 panel = 64 VGPR/lane; 256-thread blocks; wave = o-tile;
// zero LDS, zero barriers. Output bit-identical to the proven LDS version.
// ---------------------------------------------------------------------------
__launch_bounds__(256, 3)
__global__ void proj_hidden_kernel(const uint16_t* __restrict__ G,
                                   const float* __restrict__ bases,
                                   const float* __restrict__ bias,
                                   uint16_t* __restrict__ xout, int nNodes) {
    const int t    = (int)threadIdx.x;
    const int lane = t & 63;
    const int ot   = t >> 6;            // wave = o-tile (0..3)
    const int q    = lane >> 4;
    const int c    = lane & 15;

    FragU bf[16];
#pragma unroll
    for (int kb = 0; kb < 16; kb++) {
#pragma unroll
        for (int j = 0; j < 8; j++) {
            const int k = kb * 32 + q * 8 + j;
            const int i = k >> 3, b = k & 7;
            bf[kb].s[j] = (short)f2bf(bases[(size_t)(b * HDIM + i) * HDIM + ot * 16 + c]);
        }
    }
    const float bv = bias[ot * 16 + c];

    const int nTiles = (nNodes + 63) / 64;
    for (int tile = (int)blockIdx.x; tile < nTiles; tile += (int)gridDim.x) {
#pragma unroll
        for (int g = 0; g < 4; g++) {
            int arow = tile * 64 + g * 16 + c;
            if (arow > nNodes - 1) arow = nNodes - 1;
            const uint16_t* gp = G + (size_t)arow * KDIM + q * 8;

            f32x4 acc = {0.f, 0.f, 0.f, 0.f};
#pragma unroll
            for (int kb = 0; kb < 16; kb++) {
                FragU a;
                a.u = *reinterpret_cast<const uint4*>(gp + kb * 32);
                acc = __builtin_amdgcn_mfma_f32_16x16x32_bf16(a.s, bf[kb].s, acc, 0, 0, 0);
            }

            const int nbase = tile * 64 + g * 16 + q * 4;
#pragma unroll
            for (int r = 0; r < 4; r++) {
                const int node = nbase + r;
                if (node < nNodes) {
                    float v = fmaxf(acc[r] + bv, 0.f);
                    xout[(size_t)node * HDIM + ot * 16 + c] = f2bf(v);
                }
            }
        }
    }
}

__launch_bounds__(256, 3)
__global__ void proj_out_kernel(const uint16_t* __restrict__ G,
                                const float* __restrict__ bases,
                                const float* __restrict__ bias,
                                float* __restrict__ out, int nNodes) {
    const int t    = (int)threadIdx.x;
    const int lane = t & 63;
    const int w    = t >> 6;            // wave = node-group (0..3), single o-tile
    const int q    = lane >> 4;
    const int c    = lane & 15;

    FragU bf[16];
#pragma unroll
    for (int kb = 0; kb < 16; kb++) {
#pragma unroll
        for (int j = 0; j < 8; j++) {
            const int k = kb * 32 + q * 8 + j;
            const int i = k >> 3, b = k & 7;
            bf[kb].s[j] = (short)f2bf(bases[(size_t)(b * HDIM + i) * ODIM + c]);
        }
    }
    const float bv = bias[c];

    const int nTiles = (nNodes + 63) / 64;
    for (int tile = (int)blockIdx.x; tile < nTiles; tile += (int)gridDim.x) {
        int arow = tile * 64 + w * 16 + c;
        if (arow > nNodes - 1) arow = nNodes - 1;
        const uint16_t* gp = G + (size_t)arow * KDIM + q * 8;

        f32x4 acc = {0.f, 0.f, 0.f, 0.f};
#pragma unroll
        for (int kb = 0; kb < 16; kb++) {
            FragU a;
            a.u = *reinterpret_cast<const uint4*>(gp + kb * 32);
            acc = __builtin_amdgcn_mfma_f32_16x16x32_bf16(a.s, bf[kb].s, acc, 0, 0, 0);
        }

        const int nbase = tile * 64 + w * 16 + q * 4;
#pragma unroll
        for (int r = 0; r < 4; r++) {
            const int node = nbase + r;
            if (node < nNodes) out[(size_t)node * ODIM + c] = acc[r] + bv;
        }
    }
}

extern "C" void kernel_launch(void* const* d_in, const int* in_sizes, int n_in,
                              void* d_out, int out_size, void* d_ws, size_t ws_size,
                              hipStream_t stream) {
    const float* feats  = (const float*)d_in[0];
    const float* coeff0 = (const float*)d_in[1];
    const float* bases0 = (const float*)d_in[2];
    const float* bias0  = (const float*)d_in[3];
    const float* coeff1 = (const float*)d_in[4];
    const float* bases1 = (const float*)d_in[5];
    const float* bias1  = (const float*)d_in[6];
    const float* coeff2 = (const float*)d_in[7];
    const float* bases2 = (const float*)d_in[8];
    const float* bias2  = (const float*)d_in[9];
    const int*   src    = (const int*)d_in[10];
    const int*   dst    = (const int*)d_in[11];
    const int*   etype  = (const int*)d_in[12];
    const float* norm   = (const float*)d_in[13];
    float* out = (float*)d_out;

    char* base = (char*)d_ws;
    // layout: G 102.4MB | x 12.8MB | offs | cursor | bsum | bbase | rec 8MB
    uint16_t* G = (uint16_t*)base;
    uint16_t* x = (uint16_t*)(base + (size_t)NNODES * KDIM * 2);       // +102,400,000
    const size_t OFF_OFFS  = 115200000;
    const size_t OFF_CURS  = OFF_OFFS + 400016;
    const size_t OFF_BSUM  = OFF_CURS + 400016;
    const size_t OFF_BBASE = OFF_BSUM + 1024;
    const size_t OFF_REC   = OFF_BBASE + 1024;                         // 116,002,080
    int*   offs  = (int*)(base + OFF_OFFS);
    int*   curs  = (int*)(base + OFF_CURS);
    int*   bsum  = (int*)(base + OFF_BSUM);
    int*   bbase = (int*)(base + OFF_BBASE);
    uint2* rec   = (uint2*)(base + OFF_REC);

    const int nblk = (NNODES + SCAN_B - 1) / SCAN_B;   // 196 <= 256

    // ---- CSR build (graph identical across layers; built once per call)
    hipLaunchKernelGGL(zero_kernel, dim3(256), dim3(256), 0, stream, curs, NNODES);
    hipLaunchKernelGGL(hist_kernel, dim3(2048), dim3(256), 0, stream, dst, curs, NEDGES);
    hipLaunchKernelGGL(scan_partial_kernel, dim3(nblk), dim3(SCAN_B), 0, stream, curs, bsum, NNODES);
    hipLaunchKernelGGL(scan_base_kernel, dim3(1), dim3(256), 0, stream, bsum, bbase, offs, nblk, NNODES);
    hipLaunchKernelGGL(scan_final_kernel, dim3(nblk), dim3(SCAN_B), 0, stream, curs, bbase, offs, NNODES);
    hipLaunchKernelGGL(scatter_kernel, dim3(1024), dim3(256), 0, stream,
                       src, dst, etype, norm, curs, rec, NEDGES);

    // ---- x0 = bf16(feats)
    hipLaunchKernelGGL(cast_kernel, dim3(2048), dim3(256), 0, stream,
                       feats, x, NNODES * HDIM / 4);

    // ---- Layer 0
    hipLaunchKernelGGL(csr_agg_kernel, dim3(2048), dim3(256), 0, stream,
                       x, coeff0, offs, rec, G, NNODES);
    hipLaunchKernelGGL(proj_hidden_kernel, dim3(1024), dim3(256), 0, stream,
                       G, bases0, bias0, x, NNODES);
    // ---- Layer 1
    hipLaunchKernelGGL(csr_agg_kernel, dim3(2048), dim3(256), 0, stream,
                       x, coeff1, offs, rec, G, NNODES);
    hipLaunchKernelGGL(proj_hidden_kernel, dim3(1024), dim3(256), 0, stream,
                       G, bases1, bias1, x, NNODES);
    // ---- Layer 2
    hipLaunchKernelGGL(csr_agg_kernel, dim3(2048), dim3(256), 0, stream,
                       x, coeff2, offs, rec, G, NNODES);
    hipLaunchKernelGGL(proj_out_kernel, dim3(1024), dim3(256), 0, stream,
                       G, bases2, bias2, out, NNODES);
}